// Round 1
// baseline (3220.475 us; speedup 1.0000x reference)
//
#include <hip/hip_runtime.h>
#include <hip/hip_bf16.h>
#include <cstdint>
#include <cstddef>

// ---------------------------------------------------------------------------
// ConvLinearLayer fp32 baseline (round 1: correctness + profile anchor).
//
// Pipeline:
//   wsumX = 0.1 * sum_i spline_w[:,:,i]          (4 small kernels)
//   G1: a_low  = silu(x@fc1_low_bw.T)  + x@wsum1.T         [M,128]
//   G2: a_full = silu(x@fc1_full_bw.T) + x@wsum2.T         [M,256]
//   conv1+stats -> bn_relu  (b_low)
//   G3: x_low2 = MLL(b_low, fc2_low)                       [M,128]
//   conv2+stats -> bn_relu  (b_full)
//   hcat = concat(x_low2, b_full) * channel_scale          [M,384]
//   G4: t1 = relu(hcat@fus_w1.T + b1)                      [M,192]  (reuses a_full)
//   G5: hf = t1@fus_w2.T + b2                              [M,384]  (reuses hcat)
//   G6: h2 = MLL(hf, fc3)                                  [M,512]
//   conv3+stats -> d_out (pre-BN), then bn_relu + res_scale*x in-place
//
// ws layout (floats): wsum1..4, stats(1792), a_low, a_full, b_low, b_full,
// hcat, h2  -> ~418 MB total.
// ---------------------------------------------------------------------------

static constexpr int BATCH = 16;
static constexpr int NPIX  = 64 * 64;        // 4096
static constexpr int M     = BATCH * NPIX;   // 65536
static constexpr int CIN   = 512;
static constexpr int LOW   = 128;
static constexpr int FULL  = 256;
static constexpr int CAT   = 384;
static constexpr int FUS   = 192;
static constexpr int COUT  = 512;
static constexpr float BN_EPS = 1e-5f;

#define DIVUP(a, b) (((a) + (b) - 1) / (b))

// ---------------------------------------------------------------------------
// wsum[o*K+k] = 0.1 * sum_{i<10} sw[(o*K+k)*10 + i]
__global__ __launch_bounds__(256)
void spline_sum(const float* __restrict__ sw, float* __restrict__ out, int n)
{
    for (int idx = blockIdx.x * 256 + threadIdx.x; idx < n; idx += gridDim.x * 256) {
        const float* p = sw + (size_t)idx * 10;
        float s = 0.f;
#pragma unroll
        for (int i = 0; i < 10; i++) s += p[i];
        out[idx] = s * 0.1f;
    }
}

__global__ __launch_bounds__(256)
void zero_f32(float* __restrict__ p, int n)
{
    int i = blockIdx.x * 256 + threadIdx.x;
    if (i < n) p[i] = 0.f;
}

// ---------------------------------------------------------------------------
// Tiled fp32 GEMM, TN layout: out[m,o] = sum_k A[m,k] * W[o,k]   (+ epilogue)
// EPI 0: out = silu(acc_W0) + acc_W1            (MLL; W1 = pre-scaled wsum)
// EPI 1: out = relu(acc + bias)
// EPI 2: out = acc + bias
// Tile 64x64, BK=16, 256 threads, 4x4 micro-tile per thread.
// A rows r = 4*ty+i (2-way LDS bank alias = free); B cols c = tx+16j (2-way).
template<int EPI>
__global__ __launch_bounds__(256)
void gemm_fused(const float* __restrict__ A, const float* __restrict__ W0,
                const float* __restrict__ W1, const float* __restrict__ bias,
                float* __restrict__ out, int K, int O)
{
    __shared__ float As[64][20];
    __shared__ float Bs[64][20];
    __shared__ float Cs[64][20];   // spline weights (EPI==0 only)

    const int tid  = threadIdx.x;
    const int tx   = tid & 15;     // col group 0..15
    const int ty   = tid >> 4;     // row group 0..15
    const int lrow = tid >> 2;     // staging row 0..63
    const int lk4  = (tid & 3) * 4;

    const size_t arow = (size_t)(blockIdx.y * 64 + lrow) * K + lk4;
    const size_t wrow = (size_t)(blockIdx.x * 64 + lrow) * K + lk4;

    float acc[4][4]  = {};
    float accS[4][4] = {};

    for (int kt = 0; kt < K; kt += 16) {
        __syncthreads();
        *(float4*)&As[lrow][lk4] = *(const float4*)(A + arow + kt);
        *(float4*)&Bs[lrow][lk4] = *(const float4*)(W0 + wrow + kt);
        if (EPI == 0)
            *(float4*)&Cs[lrow][lk4] = *(const float4*)(W1 + wrow + kt);
        __syncthreads();

#pragma unroll
        for (int kk = 0; kk < 16; kk += 4) {
            float4 a4[4], b4[4], c4[4];
#pragma unroll
            for (int i = 0; i < 4; i++) a4[i] = *(const float4*)&As[ty * 4 + i][kk];
#pragma unroll
            for (int j = 0; j < 4; j++) b4[j] = *(const float4*)&Bs[tx + 16 * j][kk];
            if (EPI == 0) {
#pragma unroll
                for (int j = 0; j < 4; j++) c4[j] = *(const float4*)&Cs[tx + 16 * j][kk];
            }
#pragma unroll
            for (int i = 0; i < 4; i++) {
#pragma unroll
                for (int j = 0; j < 4; j++) {
                    acc[i][j] += a4[i].x * b4[j].x + a4[i].y * b4[j].y
                               + a4[i].z * b4[j].z + a4[i].w * b4[j].w;
                    if (EPI == 0)
                        accS[i][j] += a4[i].x * c4[j].x + a4[i].y * c4[j].y
                                    + a4[i].z * c4[j].z + a4[i].w * c4[j].w;
                }
            }
        }
    }

#pragma unroll
    for (int i = 0; i < 4; i++) {
        const int r = blockIdx.y * 64 + ty * 4 + i;
#pragma unroll
        for (int j = 0; j < 4; j++) {
            const int c = blockIdx.x * 64 + tx + 16 * j;
            float v;
            if (EPI == 0) {
                const float b = acc[i][j];
                v = b / (1.f + __expf(-b)) + accS[i][j];   // silu(base) + spline
            } else {
                v = acc[i][j] + bias[c];
                if (EPI == 1) v = fmaxf(v, 0.f);
            }
            out[(size_t)r * O + c] = v;
        }
    }
}

// ---------------------------------------------------------------------------
// Depthwise 3x3 SAME conv (channels-last [B,H,W,C]) + bias, writes pre-BN
// values and accumulates per-channel sum / sumsq (LDS bins -> global atomics).
template<int C>
__global__ __launch_bounds__(256)
void dwconv_stats(const float* __restrict__ in, const float* __restrict__ w,
                  const float* __restrict__ bias, float* __restrict__ out,
                  float* __restrict__ stats)
{
    __shared__ float sw[C * 9];
    __shared__ float sb[C];
    __shared__ float ssum[C];
    __shared__ float ssq[C];
    for (int i = threadIdx.x; i < C; i += 256) { sb[i] = bias[i]; ssum[i] = 0.f; ssq[i] = 0.f; }
    for (int i = threadIdx.x; i < C * 9; i += 256) sw[i] = w[i];
    __syncthreads();

    const int total = M * C;
    for (int idx = blockIdx.x * 256 + threadIdx.x; idx < total; idx += gridDim.x * 256) {
        const int c = idx & (C - 1);
        const int p = idx / C;             // b*4096 + y*64 + x
        const int x = p & 63;
        const int y = (p >> 6) & 63;
        const int b = p >> 12;
        const float* base = in + (size_t)(b << 12) * C;
        float acc = sb[c];
#pragma unroll
        for (int dy = -1; dy <= 1; dy++) {
            const int yy = y + dy;
            if ((unsigned)yy > 63u) continue;
#pragma unroll
            for (int dx = -1; dx <= 1; dx++) {
                const int xx = x + dx;
                if ((unsigned)xx > 63u) continue;
                acc += base[(size_t)((yy << 6) + xx) * C + c] * sw[c * 9 + (dy + 1) * 3 + (dx + 1)];
            }
        }
        out[idx] = acc;
        atomicAdd(&ssum[c], acc);
        atomicAdd(&ssq[c], acc * acc);
    }
    __syncthreads();
    for (int i = threadIdx.x; i < C; i += 256) {
        atomicAdd(&stats[i],     ssum[i]);
        atomicAdd(&stats[C + i], ssq[i]);
    }
}

// ---------------------------------------------------------------------------
// In-place train-mode BN + ReLU; RES adds res_scale * xres (final output).
template<int C, bool RES>
__global__ __launch_bounds__(256)
void bn_relu_apply(float* __restrict__ buf, const float* __restrict__ stats,
                   const float* __restrict__ gamma, const float* __restrict__ beta,
                   const float* __restrict__ xres, const float* __restrict__ res_scale)
{
    const float inv = 1.f / (float)M;
    const float rs  = RES ? res_scale[0] : 0.f;
    const int total = M * C;
    for (int idx = blockIdx.x * 256 + threadIdx.x; idx < total; idx += gridDim.x * 256) {
        const int c = idx & (C - 1);
        const float mu  = stats[c] * inv;
        const float var = stats[C + c] * inv - mu * mu;
        const float sc  = gamma[c] * rsqrtf(var + BN_EPS);
        float v = fmaxf((buf[idx] - mu) * sc + beta[c], 0.f);
        if (RES) v += rs * xres[idx];
        buf[idx] = v;
    }
}

// ---------------------------------------------------------------------------
// h[m, 0:128] = x_low2[m,:]*cs[0:128]; h[m,128:384] = b_full[m,:]*cs[128:384]
__global__ __launch_bounds__(256)
void concat_scale(const float* __restrict__ xl, const float* __restrict__ xf,
                  const float* __restrict__ cs, float* __restrict__ h)
{
    const int total = M * CAT;
    for (int idx = blockIdx.x * 256 + threadIdx.x; idx < total; idx += gridDim.x * 256) {
        const int c = idx % CAT;
        const int m = idx / CAT;
        const float v = (c < LOW) ? xl[m * LOW + c] : xf[m * FULL + (c - LOW)];
        h[idx] = v * cs[c];
    }
}

// ---------------------------------------------------------------------------
extern "C" void kernel_launch(void* const* d_in, const int* in_sizes, int n_in,
                              void* d_out, int out_size, void* d_ws, size_t ws_size,
                              hipStream_t stream)
{
    const float* x           = (const float*)d_in[0];
    // d_in[1]=H, d_in[2]=W (int, always 64) -- compile-time constants here.
    const float* fc1_low_bw  = (const float*)d_in[3];
    const float* fc1_low_sw  = (const float*)d_in[4];
    const float* fc2_low_bw  = (const float*)d_in[5];
    const float* fc2_low_sw  = (const float*)d_in[6];
    const float* fc1_full_bw = (const float*)d_in[7];
    const float* fc1_full_sw = (const float*)d_in[8];
    const float* fc3_bw      = (const float*)d_in[9];
    const float* fc3_sw      = (const float*)d_in[10];
    const float* fus_w1      = (const float*)d_in[11];
    const float* fus_b1      = (const float*)d_in[12];
    const float* fus_w2      = (const float*)d_in[13];
    const float* fus_b2      = (const float*)d_in[14];
    const float* cscale      = (const float*)d_in[15];
    const float* dw1_w       = (const float*)d_in[16];
    const float* dw1_b       = (const float*)d_in[17];
    const float* dw1_g       = (const float*)d_in[18];
    const float* dw1_beta    = (const float*)d_in[19];
    const float* dw2_w       = (const float*)d_in[20];
    const float* dw2_b       = (const float*)d_in[21];
    const float* dw2_g       = (const float*)d_in[22];
    const float* dw2_beta    = (const float*)d_in[23];
    const float* dw3_w       = (const float*)d_in[24];
    const float* dw3_b       = (const float*)d_in[25];
    const float* dw3_g       = (const float*)d_in[26];
    const float* dw3_beta    = (const float*)d_in[27];
    const float* res_scale   = (const float*)d_in[28];

    float* out = (float*)d_out;
    float* ws  = (float*)d_ws;

    // ---- workspace layout (floats) ----
    float* wsum1 = ws;                       // 128*512
    float* wsum2 = wsum1 + 128 * 512;        // 256*512
    float* wsum3 = wsum2 + 256 * 512;        // 128*128
    float* wsum4 = wsum3 + 128 * 128;        // 512*384
    float* stats = wsum4 + 512 * 384;        // 1792 used, pad to 2048
    float* a_low  = stats + 2048;            // [M,128]
    float* a_full = a_low  + (size_t)M * LOW;   // [M,256]
    float* b_low  = a_full + (size_t)M * FULL;  // [M,128]
    float* b_full = b_low  + (size_t)M * LOW;   // [M,256]
    float* hcat   = b_full + (size_t)M * FULL;  // [M,384]
    float* h2     = hcat   + (size_t)M * CAT;   // [M,512]
    float* t1 = a_full;   // reuse: a_full dead after conv2
    float* hf = hcat;     // reuse: hcat dead after fus1

    float* stats1 = stats;                       // 2*128
    float* stats2 = stats + 2 * LOW;             // 2*256
    float* stats3 = stats + 2 * LOW + 2 * FULL;  // 2*512

    // ws is poisoned 0xAA each call: zero the atomic accumulators.
    zero_f32<<<DIVUP(1792, 256), 256, 0, stream>>>(stats, 1792);

    // spline weight sums (pre-scaled by 1/K_SPLINE)
    spline_sum<<<256, 256, 0, stream>>>(fc1_low_sw,  wsum1, 128 * 512);
    spline_sum<<<512, 256, 0, stream>>>(fc1_full_sw, wsum2, 256 * 512);
    spline_sum<<< 64, 256, 0, stream>>>(fc2_low_sw,  wsum3, 128 * 128);
    spline_sum<<<768, 256, 0, stream>>>(fc3_sw,      wsum4, 512 * 384);

    // G1/G2: first MLLs from x
    gemm_fused<0><<<dim3(LOW  / 64, M / 64), 256, 0, stream>>>(x, fc1_low_bw,  wsum1, nullptr, a_low,  CIN, LOW);
    gemm_fused<0><<<dim3(FULL / 64, M / 64), 256, 0, stream>>>(x, fc1_full_bw, wsum2, nullptr, a_full, CIN, FULL);

    // low branch: conv1 -> bn -> MLL2
    dwconv_stats<LOW ><<<2048, 256, 0, stream>>>(a_low, dw1_w, dw1_b, b_low, stats1);
    bn_relu_apply<LOW,  false><<<2048, 256, 0, stream>>>(b_low, stats1, dw1_g, dw1_beta, nullptr, nullptr);
    gemm_fused<0><<<dim3(LOW / 64, M / 64), 256, 0, stream>>>(b_low, fc2_low_bw, wsum3, nullptr, a_low, LOW, LOW);

    // full branch: conv2 -> bn
    dwconv_stats<FULL><<<2048, 256, 0, stream>>>(a_full, dw2_w, dw2_b, b_full, stats2);
    bn_relu_apply<FULL, false><<<2048, 256, 0, stream>>>(b_full, stats2, dw2_g, dw2_beta, nullptr, nullptr);

    // concat * channel_scale, fusion MLP
    concat_scale<<<2048, 256, 0, stream>>>(a_low, b_full, cscale, hcat);
    gemm_fused<1><<<dim3(FUS / 64, M / 64), 256, 0, stream>>>(hcat, fus_w1, nullptr, fus_b1, t1, CAT, FUS);
    gemm_fused<2><<<dim3(CAT / 64, M / 64), 256, 0, stream>>>(t1,   fus_w2, nullptr, fus_b2, hf, FUS, CAT);

    // fc3 MLL, conv3 -> d_out (pre-BN), bn+relu+residual in-place
    gemm_fused<0><<<dim3(COUT / 64, M / 64), 256, 0, stream>>>(hf, fc3_bw, wsum4, nullptr, h2, CAT, COUT);
    dwconv_stats<COUT><<<2048, 256, 0, stream>>>(h2, dw3_w, dw3_b, out, stats3);
    bn_relu_apply<COUT, true><<<2048, 256, 0, stream>>>(out, stats3, dw3_g, dw3_beta, x, res_scale);
}